// Round 11
// baseline (76.924 us; speedup 1.0000x reference)
//
#include <hip/hip_runtime.h>

#define NN     4096
#define TT     3
#define DD     20
#define EE     131072
#define ADIM   128
#define NEG    0.2f
#define NEDGE  (TT * EE)               // 393216 edges
#define CAP    512                     // bucket/CSR segment per row (max ~260 used)
#define CSTR   16                      // cnt stride in u32 -> one 64B line per row

// ---- k_scat: one thread per edge -> both directed bucket entries ------------
// rank = padded per-row global atomicAdd (one cache line per row). Duplicate
// edges and self-loops produce duplicate entries; k_l0's OR-dedup erases them.
// Blocks 0..1023 additionally compute s0 = inputs @ lin_w.T + lin_b.
__global__ __launch_bounds__(256) void k_scat(const int* __restrict__ el,
                                              unsigned int* __restrict__ cnt,
                                              unsigned short* __restrict__ bucket,
                                              const float* __restrict__ inputs,
                                              const float* __restrict__ lin_w,
                                              const float* __restrict__ lin_b,
                                              float* __restrict__ s0) {
    int i = blockIdx.x * 256 + threadIdx.x;        // edge index, exactly NEDGE
    int t = i >> 17;                               // EE = 2^17
    int e = i & (EE - 1);
    unsigned int a = (unsigned int)el[(t * 2) * EE + e];
    unsigned int b = (unsigned int)el[(t * 2 + 1) * EE + e];
    unsigned int ts = (unsigned int)t << 12;

    unsigned int ra = atomicAdd(&cnt[a * CSTR], 1u);
    if (ra < CAP) bucket[a * CAP + ra] = (unsigned short)(b | ts);
    unsigned int rb = atomicAdd(&cnt[b * CSTR], 1u);
    if (rb < CAP) bucket[b * CAP + rb] = (unsigned short)(a | ts);

    if (blockIdx.x < NN / 4) {                     // fused score init
        int wid = threadIdx.x >> 6, lane = threadIdx.x & 63;
        int row = blockIdx.x * 4 + wid;
        const float* rp = inputs + row * ADIM;
        float v = rp[lane] * lin_w[lane] + rp[lane + 64] * lin_w[lane + 64];
        #pragma unroll
        for (int off = 32; off > 0; off >>= 1) v += __shfl_down(v, off);
        if (lane == 0) s0[row] = v + lin_b[0];
    }
}

// ---- k_l0: per-row LDS nibble-mask dedup + layer 0 + compact CSR emit -------
__global__ __launch_bounds__(256) void k_l0(const unsigned int* __restrict__ cnt,
                                            const unsigned short* __restrict__ bucket,
                                            unsigned int* __restrict__ cnt2,
                                            unsigned short* __restrict__ entries2,
                                            const float* __restrict__ s_in,
                                            const float* __restrict__ att_w,
                                            const float* __restrict__ edge_emb,
                                            float* __restrict__ s_out) {
    __shared__ unsigned int mask[4][512];          // 2 KB nibble-mask per wave/row
    __shared__ float lut0[8], lut1[8], wc[4], Sred[4];
    int tid = threadIdx.x, wid = tid >> 6, lane = tid & 63;

    if (tid < 16) {                                // layer 0 constants
        int h = tid >> 3, m = tid & 7;
        const float* w = att_w + h * (DD + 2);
        float e0 = 0.f, e1 = 0.f, e2 = 0.f;
        #pragma unroll
        for (int d = 0; d < DD; d++) {
            float wd = w[1 + d];
            e0 += edge_emb[0 * DD + d] * wd;
            e1 += edge_emb[1 * DD + d] * wd;
            e2 += edge_emb[2 * DD + d] * wd;
        }
        float l = (m & 1 ? e0 : 0.f) + (m & 2 ? e1 : 0.f) + (m & 4 ? e2 : 0.f);
        if (h) lut1[m] = l; else lut0[m] = l;
        if (m == 0) { wc[h] = w[0]; wc[2 + h] = w[DD + 1]; }
    }

    float ps = 0.f;                                // S = sum(s_in), deterministic
    for (int j = tid; j < NN; j += 256) ps += s_in[j];
    #pragma unroll
    for (int off = 32; off > 0; off >>= 1) ps += __shfl_down(ps, off);
    if (lane == 0) Sred[wid] = ps;

    for (int i = lane; i < 512; i += 64) mask[wid][i] = 0u;
    int row = blockIdx.x * 4 + wid;
    unsigned int n = min(cnt[row * CSTR], (unsigned int)CAP);
    const unsigned short* brow = bucket + (size_t)row * CAP;
    for (unsigned int i = lane; i < n; i += 64) {
        unsigned int v = brow[i];
        unsigned int col = v & 0xFFFu, t = v >> 12;
        atomicOr(&mask[wid][col >> 3], 1u << (((col & 7u) << 2) + t));
    }
    __syncthreads();                               // covers lut/Sred/mask
    float S = Sred[0] + Sred[1] + Sred[2] + Sred[3];

    float si = s_in[row];
    float a0 = wc[0] * si, a1 = wc[1] * si;
    float b0 = wc[2],      b1 = wc[3];
    unsigned short* erow = entries2 + (size_t)row * CAP;

    float num0 = 0.f, den0 = 0.f, num1 = 0.f, den1 = 0.f;
    unsigned int base = 0;
    #pragma unroll
    for (int k = 0; k < 8; k++) {                  // 512 words, 8 per lane
        unsigned int w = mask[wid][k * 64 + lane];
        unsigned int y = w | (w >> 1); y |= (y >> 2); y &= 0x11111111u;
        unsigned int cc = __popc(y);
        unsigned int p = cc;                       // wave-inclusive scan
        #pragma unroll
        for (int off = 1; off < 64; off <<= 1) {
            unsigned int v = __shfl_up(p, off);
            if (lane >= off) p += v;
        }
        unsigned int pos = base + (p - cc);        // exclusive prefix
        if (w) {
            int jb = (k * 64 + lane) << 3;
            #pragma unroll
            for (int kk = 0; kk < 8; kk++) {
                unsigned int nib = (w >> (kk * 4)) & 0xFu;
                if (!nib) continue;
                int j = jb + kk;
                float c2 = (float)__popc(nib);
                float sj = s_in[j];
                float l0 = c2 * (a0 + b0 * sj) + lut0[nib];
                l0 = (l0 > 0.f) ? l0 : NEG * l0;
                float x0 = __expf(l0) - 1.0f;
                num0 += x0 * sj; den0 += x0;
                float l1 = c2 * (a1 + b1 * sj) + lut1[nib];
                l1 = (l1 > 0.f) ? l1 : NEG * l1;
                float x1 = __expf(l1) - 1.0f;
                num1 += x1 * sj; den1 += x1;
                erow[pos++] = (unsigned short)(j | (nib << 12));
            }
        }
        base += __shfl(p, 63);
    }
    if (lane == 0) cnt2[row] = base;

    #pragma unroll
    for (int off = 32; off > 0; off >>= 1) {
        num0 += __shfl_down(num0, off); den0 += __shfl_down(den0, off);
        num1 += __shfl_down(num1, off); den1 += __shfl_down(den1, off);
    }
    if (lane == 0) {
        float o0 = (S + num0) / ((float)NN + den0);
        float o1 = (S + num1) / ((float)NN + den1);
        s_out[row] = 0.5f * (o0 + o1);
    }
}

// ---- k_l1: layer 1 over compact CSR (row per wave) --------------------------
__global__ __launch_bounds__(256) void k_l1(const unsigned int* __restrict__ cnt2,
                                            const unsigned short* __restrict__ entries2,
                                            const float* __restrict__ s_in,
                                            const float* __restrict__ att_w,
                                            const float* __restrict__ edge_emb,
                                            float* __restrict__ s_out) {
    __shared__ float lut0[8], lut1[8], wc[4], Sred[4];
    int tid = threadIdx.x;

    if (tid < 16) {                                // layer 1 constants
        int h = tid >> 3, m = tid & 7;
        const float* w = att_w + (2 + h) * (DD + 2);
        float e0 = 0.f, e1 = 0.f, e2 = 0.f;
        #pragma unroll
        for (int d = 0; d < DD; d++) {
            float wd = w[1 + d];
            e0 += edge_emb[0 * DD + d] * wd;
            e1 += edge_emb[1 * DD + d] * wd;
            e2 += edge_emb[2 * DD + d] * wd;
        }
        float l = (m & 1 ? e0 : 0.f) + (m & 2 ? e1 : 0.f) + (m & 4 ? e2 : 0.f);
        if (h) lut1[m] = l; else lut0[m] = l;
        if (m == 0) { wc[h] = w[0]; wc[2 + h] = w[DD + 1]; }
    }

    float ps = 0.f;
    for (int j = tid; j < NN; j += 256) ps += s_in[j];
    #pragma unroll
    for (int off = 32; off > 0; off >>= 1) ps += __shfl_down(ps, off);
    int wid = tid >> 6, lane = tid & 63;
    if (lane == 0) Sred[wid] = ps;
    __syncthreads();
    float S = Sred[0] + Sred[1] + Sred[2] + Sred[3];

    int row = blockIdx.x * 4 + wid;
    float si = s_in[row];
    float a0 = wc[0] * si, a1 = wc[1] * si;
    float b0 = wc[2],      b1 = wc[3];
    unsigned int n = cnt2[row];
    const unsigned short* ent = entries2 + (size_t)row * CAP;

    float num0 = 0.f, den0 = 0.f, num1 = 0.f, den1 = 0.f;
    for (unsigned int i = lane; i < n; i += 64) {
        unsigned int v = ent[i];
        unsigned int j = v & 0xFFFu, nib = v >> 12;
        float c  = (float)__popc(nib);
        float sj = s_in[j];
        float l0 = c * (a0 + b0 * sj) + lut0[nib];
        l0 = (l0 > 0.f) ? l0 : NEG * l0;
        float x0 = __expf(l0) - 1.0f;
        num0 += x0 * sj; den0 += x0;
        float l1 = c * (a1 + b1 * sj) + lut1[nib];
        l1 = (l1 > 0.f) ? l1 : NEG * l1;
        float x1 = __expf(l1) - 1.0f;
        num1 += x1 * sj; den1 += x1;
    }

    #pragma unroll
    for (int off = 32; off > 0; off >>= 1) {
        num0 += __shfl_down(num0, off); den0 += __shfl_down(den0, off);
        num1 += __shfl_down(num1, off); den1 += __shfl_down(den1, off);
    }
    if (lane == 0) {
        float o0 = (S + num0) / ((float)NN + den0);
        float o1 = (S + num1) / ((float)NN + den1);
        s_out[row] = 0.5f * (o0 + o1);
    }
}

// ---- host-side launcher ------------------------------------------------------
extern "C" void kernel_launch(void* const* d_in, const int* in_sizes, int n_in,
                              void* d_out, int out_size, void* d_ws, size_t ws_size,
                              hipStream_t stream) {
    const float* inputs   = (const float*)d_in[0];
    const float* lin_w    = (const float*)d_in[1];
    const float* lin_b    = (const float*)d_in[2];
    const float* edge_emb = (const float*)d_in[3];
    const float* att_w    = (const float*)d_in[4];
    const int*   el       = (const int*)d_in[5];
    float* out = (float*)d_out;

    char* ws = (char*)d_ws;
    unsigned int*   cnt      = (unsigned int*)ws;                         // 256 KB (padded)
    unsigned short* bucket   = (unsigned short*)(ws + 262144);            // 4 MB
    unsigned short* entries2 = (unsigned short*)(ws + 4456448);           // 4 MB
    unsigned int*   cnt2     = (unsigned int*)(ws + 8650752);             // 16 KB
    float*          s0       = (float*)(ws + 8667136);                    // 16 KB
    float*          s1       = (float*)(ws + 8683520);                    // 16 KB

    hipMemsetAsync(cnt, 0, NN * CSTR * sizeof(unsigned int), stream);
    k_scat<<<NEDGE / 256, 256, 0, stream>>>(el, cnt, bucket, inputs, lin_w, lin_b, s0);
    k_l0  <<<1024, 256, 0, stream>>>(cnt, bucket, cnt2, entries2, s0, att_w, edge_emb, s1);
    k_l1  <<<1024, 256, 0, stream>>>(cnt2, entries2, s1, att_w, edge_emb, out);
}